// Round 11
// baseline (405.815 us; speedup 1.0000x reference)
//
#include <hip/hip_runtime.h>
#include <math.h>

#define NSLOTS 50
#define T 101
#define SEQ 2048
#define CHUNK 16

// v + dpp_permuted(v), pure VALU
template<int CTRL>
__device__ __forceinline__ float dpp_xadd(float v) {
    int x = __builtin_amdgcn_update_dpp(0, __float_as_int(v), CTRL, 0xF, 0xF, true);
    return v + __int_as_float(x);
}

// Full 64-lane sum -> wave-uniform scalar (validated r8/r9, absmax 0.0)
__device__ __forceinline__ float wsum64(float v) {
    v = dpp_xadd<0xB1>(v);    // xor 1
    v = dpp_xadd<0x4E>(v);    // xor 2
    v = dpp_xadd<0x141>(v);   // xor 4 (row_half_mirror)
    v = dpp_xadd<0x140>(v);   // xor 8 (row_mirror)
    v = dpp_xadd<0x142>(v);   // row_bcast15
    v = dpp_xadd<0x143>(v);   // row_bcast31
    int s = __builtin_amdgcn_readlane(__float_as_int(v), 63);
    return __int_as_float(s);
}

__device__ __forceinline__ void gl_lds(const float* g, float* lds) {
#if __has_builtin(__builtin_amdgcn_global_load_lds)
    __builtin_amdgcn_global_load_lds((const __attribute__((address_space(1))) void*)g,
        (__attribute__((address_space(3))) void*)lds, 4, 0, 0);
#else
    lds[threadIdx.x & 63] = *g;
#endif
}

__global__ __launch_bounds__(192, 1) void crf_nll_kernel(
    const float* __restrict__ feats,      // [B,S,T]
    const float* __restrict__ cdt,        // [3,5] log-probs
    const float* __restrict__ start_t,    // [T]
    const float* __restrict__ stop_t,     // [T]
    const int*   __restrict__ mask,       // [B,S]
    const int*   __restrict__ tags,       // [B,S]
    float*       __restrict__ out)        // [B]
{
    const int bid = blockIdx.x, tid = threadIdx.x;
    const int wave = tid >> 6, l = tid & 63;
    const int b0 = 2 * bid, b1 = 2 * bid + 1;
    const float* fbA = feats + (size_t)b0 * SEQ * T;
    const float* fbB = feats + (size_t)b1 * SEQ * T;
    const int* mbA = mask + (size_t)b0 * SEQ;
    const int* mbB = mask + (size_t)b1 * SEQ;
    const int* tbA = tags + (size_t)b0 * SEQ;
    const int* tbB = tags + (size_t)b1 * SEQ;

    __shared__ float LA[64 * 128];   // ring A: step t -> slot (t-1)&63
    __shared__ float LB[64 * 128];   // ring B
    __shared__ float res[4];         // fwdA, goldA, fwdB, goldB

    // ---- lengths (all waves; mask is a prefix of ones) ----
    float mca = 0.f, mcb = 0.f;
    for (int t = l; t < SEQ; t += 64) { mca += (float)mbA[t]; mcb += (float)mbB[t]; }
    const int lenA = (int)(wsum64(mca) + 0.5f);
    const int lenB = (int)(wsum64(mcb) + 0.5f);
    const int nsA = lenA - 1, nsB = lenB - 1;
    const int nsMin = (nsA < nsB) ? nsA : nsB;
    const int nperA = (nsA + CHUNK - 1) / CHUNK, nperB = (nsB + CHUNK - 1) / CHUNK;
    const int nper  = (nperA > nperB) ? nperA : nperB;
    const int nfullzip = ((nsA < nsB ? nsA : nsB)) / CHUNK;

    const float actm = (l < NSLOTS) ? 1.f : 0.f;
    const int aB = (2*l+1 <= 100) ? 2*l+1 : 100;
    const int aI = (2*l+2 <= 100) ? 2*l+2 : 100;
    const int s1 = (2*l+1 <= 100) ? 2*l+1 : 0;
    const int s2 = (2*l+2 <= 100) ? 2*l+2 : 0;

    const float pOO=__expf(cdt[0]),  pOB=__expf(cdt[1]),  pOI=__expf(cdt[2]);
    const float pBO=__expf(cdt[5]),  pBBs=__expf(cdt[6]), pBIs=__expf(cdt[7]),
                pBBd=__expf(cdt[8]), pBId=__expf(cdt[9]);
    const float pIO=__expf(cdt[10]), pIBs=__expf(cdt[11]), pIIs=__expf(cdt[12]),
                pIBd=__expf(cdt[13]), pIId=__expf(cdt[14]);
    const float dBB=pBBs-pBBd, dIB=pIBs-pIBd, dBI=pBIs-pBId, dII=pIIs-pIId;

    // consumer state per batch (r9-verbatim semantics)
    float xaB=0.f, xaI=0.f, xaO=1.f, uaB=0.f, uaI=0.f, pOOxOa=pOO, accFa=0.f;
    float xbB=0.f, xbI=0.f, xbO=1.f, ubB=0.f, ubI=0.f, pOOxOb=pOO, accFb=0.f;
    int accEa=0, accEb=0;
    float f0aB=0,f0aI=0,f0aO=0,f1aB=0,f1aI=0,f1aO=0;
    float f0bB=0,f0bI=0,f0bO=0,f1bB=0,f1bI=0,f1bO=0;
    float gsA=0.f, gsB=0.f;

    // single-batch r9 step (for mixed-length tail periods)
    auto step_one = [&](float f0B, float f0I, float f0O,
                        float& xB, float& xI, float& xO,
                        float& uB, float& uI, float& pOOxO,
                        float& accF, int& accE) {
        float gB = actm * __expf(f0B - f0O);
        float gI = actm * __expf(f0I - f0O);
        int   ke = ((__float_as_int(xO) >> 23) & 0xFF) - 127;
        float r  = __int_as_float((127 - ke) << 23);
        accE += ke;
        float XB = wsum64(xB);
        float XI = wsum64(xI);
        float NO = __builtin_fmaf(XI,pIO, __builtin_fmaf(XB,pBO, pOOxO));
        float NB = gB * __builtin_fmaf(XI,pIBd, __builtin_fmaf(XB,pBBd, uB));
        float NI = gI * __builtin_fmaf(XI,pIId, __builtin_fmaf(XB,pBId, uI));
        xB = NB * r; xI = NI * r; xO = NO * r;
        pOOxO = pOO * xO;
        uB = __builtin_fmaf(xB, dBB, __builtin_fmaf(xI, dIB, pOB * xO));
        uI = __builtin_fmaf(xB, dBI, __builtin_fmaf(xI, dII, pOI * xO));
        accF += f0O;
    };

    auto gold_term = [&](const int* tbX, const float* LX, int t) -> float {
        int tg = tbX[t], tp = tbX[t - 1];
        int c1 = (tp == 0) ? 0 : ((tp & 1) ? 1 : 2);
        int c2 = (tg == 0) ? 0 : ((tg & 1) ? 1 : 2);
        int si = (tp - 1) >> 1, sj = (tg - 1) >> 1;
        int t1 = (tp != 0 && si != sj) ? ((c2 == 0) ? 0 : c2 + 2) : c2;
        float v = cdt[c1 * 5 + t1];
        int idx = (tg == 0) ? 50 : ((tg & 1) ? ((tg - 1) >> 1) : (64 + ((tg - 2) >> 1)));
        v += LX[(((t - 1) & 63) << 7) + idx];
        return v;
    };

    if (wave == 1) {
        // stage chunks 0,1 for both batches
        #pragma unroll
        for (int k = 0; k < 2*CHUNK; ++k) {
            const float* rowA = fbA + (size_t)(1 + k) * T;
            const float* rowB = fbB + (size_t)(1 + k) * T;
            float* dA = &LA[(size_t)k * 128];
            float* dB = &LB[(size_t)k * 128];
            gl_lds(rowA + s1, dA);       gl_lds(rowB + s1, dB);
            gl_lds(rowA + s2, dA + 64);  gl_lds(rowB + s2, dB + 64);
        }
    } else if (wave == 2) {
        if (l == 0) {
            int tg0 = tbA[0]; gsA = fbA[tg0] + start_t[tg0];
            int th0 = tbB[0]; gsB = fbB[th0] + start_t[th0];
        }
    } else {
        float pO0a = fbA[0] + start_t[0];
        float pO0b = fbB[0] + start_t[0];
        xaB = actm * __expf(fbA[aB] + start_t[aB] - pO0a);
        xbB = actm * __expf(fbB[aB] + start_t[aB] - pO0b);
        xaI = actm * __expf(fbA[aI] + start_t[aI] - pO0a);
        xbI = actm * __expf(fbB[aI] + start_t[aI] - pO0b);
        accFa = pO0a; accFb = pO0b;
        uaB = __builtin_fmaf(xaB, dBB, __builtin_fmaf(xaI, dIB, pOB));
        ubB = __builtin_fmaf(xbB, dBB, __builtin_fmaf(xbI, dIB, pOB));
        uaI = __builtin_fmaf(xaB, dBI, __builtin_fmaf(xaI, dII, pOI));
        ubI = __builtin_fmaf(xbB, dBI, __builtin_fmaf(xbI, dII, pOI));
    }
    __syncthreads();   // chunks 0,1 staged

    if (wave == 0) {   // pipeline fill: steps 1,2 for both batches
        f0aB = LA[l];       f0aI = LA[64 + l];       f0aO = LA[50];
        f0bB = LB[l];       f0bI = LB[64 + l];       f0bO = LB[50];
        f1aB = LA[128 + l]; f1aI = LA[128 + 64 + l]; f1aO = LA[128 + 50];
        f1bB = LB[128 + l]; f1bI = LB[128 + 64 + l]; f1bO = LB[128 + 50];
    }

#define STEP_ZIP(CHECKED)                                                      \
    {                                                                          \
        const int t  = 1 + p * CHUNK + k;                                      \
        const int w2 = ((t + 1) & 63) << 7;                                    \
        float naB = LA[w2 + l],      nbB = LB[w2 + l];                         \
        float naI = LA[w2 + 64 + l], nbI = LB[w2 + 64 + l];                    \
        float naO = LA[w2 + 50],     nbO = LB[w2 + 50];                        \
        if (!(CHECKED) || t <= nsMin) {                                        \
            float gaB = actm * __expf(f0aB - f0aO);                            \
            float gbB = actm * __expf(f0bB - f0bO);                            \
            float gaI = actm * __expf(f0aI - f0aO);                            \
            float gbI = actm * __expf(f0bI - f0bO);                            \
            int kea = ((__float_as_int(xaO) >> 23) & 0xFF) - 127;              \
            int keb = ((__float_as_int(xbO) >> 23) & 0xFF) - 127;              \
            float ra = __int_as_float((127 - kea) << 23);                      \
            float rb = __int_as_float((127 - keb) << 23);                      \
            accEa += kea; accEb += keb;                                        \
            float XaB = wsum64(xaB);                                           \
            float XbB = wsum64(xbB);                                           \
            float XaI = wsum64(xaI);                                           \
            float XbI = wsum64(xbI);                                           \
            float NaO = __builtin_fmaf(XaI,pIO, __builtin_fmaf(XaB,pBO, pOOxOa)); \
            float NbO = __builtin_fmaf(XbI,pIO, __builtin_fmaf(XbB,pBO, pOOxOb)); \
            float NaB = gaB * __builtin_fmaf(XaI,pIBd, __builtin_fmaf(XaB,pBBd, uaB)); \
            float NbB = gbB * __builtin_fmaf(XbI,pIBd, __builtin_fmaf(XbB,pBBd, ubB)); \
            float NaI = gaI * __builtin_fmaf(XaI,pIId, __builtin_fmaf(XaB,pBId, uaI)); \
            float NbI = gbI * __builtin_fmaf(XbI,pIId, __builtin_fmaf(XbB,pBId, ubI)); \
            xaB = NaB * ra;  xbB = NbB * rb;                                   \
            xaI = NaI * ra;  xbI = NbI * rb;                                   \
            xaO = NaO * ra;  xbO = NbO * rb;                                   \
            pOOxOa = pOO * xaO;  pOOxOb = pOO * xbO;                           \
            uaB = __builtin_fmaf(xaB, dBB, __builtin_fmaf(xaI, dIB, pOB * xaO)); \
            ubB = __builtin_fmaf(xbB, dBB, __builtin_fmaf(xbI, dIB, pOB * xbO)); \
            uaI = __builtin_fmaf(xaB, dBI, __builtin_fmaf(xaI, dII, pOI * xaO)); \
            ubI = __builtin_fmaf(xbB, dBI, __builtin_fmaf(xbI, dII, pOI * xbO)); \
            accFa += f0aO; accFb += f0bO;                                      \
        } else {                                                               \
            if (t <= nsA) step_one(f0aB,f0aI,f0aO, xaB,xaI,xaO,                \
                                   uaB,uaI,pOOxOa, accFa,accEa);               \
            if (t <= nsB) step_one(f0bB,f0bI,f0bO, xbB,xbI,xbO,                \
                                   ubB,ubI,pOOxOb, accFb,accEb);               \
        }                                                                      \
        f0aB=f1aB; f0aI=f1aI; f0aO=f1aO; f1aB=naB; f1aI=naI; f1aO=naO;         \
        f0bB=f1bB; f0bI=f1bI; f0bO=f1bO; f1bB=nbB; f1bI=nbI; f1bO=nbO;         \
    }

    for (int p = 0; p < nper; ++p) {
        if (wave == 0) {
            if (p < nfullzip) {
                #pragma unroll
                for (int k = 0; k < CHUNK; ++k) STEP_ZIP(false)
            } else {
                #pragma unroll
                for (int k = 0; k < CHUNK; ++k) STEP_ZIP(true)
            }
        } else if (wave == 1) {
            const int ci = p + 2;                  // stage chunk p+2, both batches
            #pragma unroll
            for (int k = 0; k < CHUNK; ++k) {
                int tt = 1 + ci * CHUNK + k;
                int tc = (tt < SEQ) ? tt : (SEQ - 1);
                const float* rowA = fbA + (size_t)tc * T;
                const float* rowB = fbB + (size_t)tc * T;
                float* dA = &LA[(size_t)((ci * CHUNK + k) & 63) * 128];
                float* dB = &LB[(size_t)((ci * CHUNK + k) & 63) * 128];
                gl_lds(rowA + s1, dA);       gl_lds(rowB + s1, dB);
                gl_lds(rowA + s2, dA + 64);  gl_lds(rowB + s2, dB + 64);
            }
        } else {
            // gold wave: chunk p-1 of both batches (rows live until period p+1)
            if (p >= 1 && l < CHUNK) {
                int t = 1 + (p - 1) * CHUNK + l;
                if (t <= nsA) gsA += gold_term(tbA, LA, t);
                if (t <= nsB) gsB += gold_term(tbB, LB, t);
            }
        }
        __syncthreads();
    }
#undef STEP_ZIP

    if (wave == 0) {
        float Wa = actm * (xaB * __expf(stop_t[aB]) + xaI * __expf(stop_t[aI]));
        float Wb = actm * (xbB * __expf(stop_t[aB]) + xbI * __expf(stop_t[aI]));
        float totA = wsum64(Wa) + xaO * __expf(stop_t[0]);
        float totB = wsum64(Wb) + xbO * __expf(stop_t[0]);
        float fwdA = accFa + 0.69314718055994530942f * (float)accEa + __logf(totA);
        float fwdB = accFb + 0.69314718055994530942f * (float)accEb + __logf(totB);
        if (l == 0) { res[0] = fwdA; res[2] = fwdB; }
    } else if (wave == 2) {
        // final chunks (nper-1): rows still intact after the loop
        if (l < CHUNK) {
            int t = 1 + (nper - 1) * CHUNK + l;
            if (t >= 1 && t <= nsA) gsA += gold_term(tbA, LA, t);
            if (t >= 1 && t <= nsB) gsB += gold_term(tbB, LB, t);
        }
        float goldA = wsum64(gsA);
        float goldB = wsum64(gsB);
        if (l == 0) {
            res[1] = goldA + stop_t[tbA[lenA - 1]];
            res[3] = goldB + stop_t[tbB[lenB - 1]];
        }
    }
    __syncthreads();
    if (tid == 0) {
        out[b0] = res[0] - res[1];
        out[b1] = res[2] - res[3];
    }
}

extern "C" void kernel_launch(void* const* d_in, const int* in_sizes, int n_in,
                              void* d_out, int out_size, void* d_ws, size_t ws_size,
                              hipStream_t stream) {
    const float* feats   = (const float*)d_in[0];
    const float* cdt     = (const float*)d_in[1];
    const float* start_t = (const float*)d_in[2];
    const float* stop_t  = (const float*)d_in[3];
    const int*   mask    = (const int*)d_in[4];
    const int*   tags    = (const int*)d_in[5];
    float* out = (float*)d_out;

    crf_nll_kernel<<<128, 192, 0, stream>>>(feats, cdt, start_t, stop_t, mask, tags, out);
}

// Round 12
// 221.418 us; speedup vs baseline: 1.8328x; 1.8328x over previous
//
#include <hip/hip_runtime.h>
#include <math.h>

#define NSLOTS 50
#define T 101
#define SEQ 2048
#define CHUNK 16

// v + dpp_permuted(v), pure VALU
template<int CTRL>
__device__ __forceinline__ float dpp_xadd(float v) {
    int x = __builtin_amdgcn_update_dpp(0, __float_as_int(v), CTRL, 0xF, 0xF, true);
    return v + __int_as_float(x);
}

// Full 64-lane sum -> wave-uniform scalar (validated r8/r9, absmax 0.0)
__device__ __forceinline__ float wsum64(float v) {
    v = dpp_xadd<0xB1>(v);    // xor 1
    v = dpp_xadd<0x4E>(v);    // xor 2
    v = dpp_xadd<0x141>(v);   // xor 4 (row_half_mirror)
    v = dpp_xadd<0x140>(v);   // xor 8 (row_mirror)
    v = dpp_xadd<0x142>(v);   // row_bcast15
    v = dpp_xadd<0x143>(v);   // row_bcast31
    int s = __builtin_amdgcn_readlane(__float_as_int(v), 63);
    return __int_as_float(s);
}

__device__ __forceinline__ void gl_lds(const float* g, float* lds) {
#if __has_builtin(__builtin_amdgcn_global_load_lds)
    __builtin_amdgcn_global_load_lds((const __attribute__((address_space(1))) void*)g,
        (__attribute__((address_space(3))) void*)lds, 4, 0, 0);
#else
    lds[threadIdx.x & 63] = *g;
#endif
}

__global__ __launch_bounds__(192, 1) void crf_nll_kernel(
    const float* __restrict__ feats,      // [B,S,T]
    const float* __restrict__ cdt,        // [3,5] log-probs
    const float* __restrict__ start_t,    // [T]
    const float* __restrict__ stop_t,     // [T]
    const int*   __restrict__ mask,       // [B,S]
    const int*   __restrict__ tags,       // [B,S]
    float*       __restrict__ out)        // [B]
{
    const int b = blockIdx.x, tid = threadIdx.x;
    const int wave = tid >> 6, l = tid & 63;
    const float* fb = feats + (size_t)b * SEQ * T;
    const int*   mb = mask + (size_t)b * SEQ;
    const int*   tb = tags + (size_t)b * SEQ;

    __shared__ float S[64 * 128];   // ring: step t -> slot (t-1)&63
    __shared__ float res[2];

    // ---- length (all waves; mask is a prefix of ones) ----
    float mc = 0.f;
    for (int t = l; t < SEQ; t += 64) mc += (float)mb[t];
    const int len    = (int)(wsum64(mc) + 0.5f);
    const int nsteps = len - 1;
    const int nper   = (nsteps + CHUNK - 1) / CHUNK;
    const int nfull  = nsteps / CHUNK;

    const float actm = (l < NSLOTS) ? 1.f : 0.f;
    const int aB = (2*l+1 <= 100) ? 2*l+1 : 100;
    const int aI = (2*l+2 <= 100) ? 2*l+2 : 100;
    const int s1 = (2*l+1 <= 100) ? 2*l+1 : 0;
    const int s2 = (2*l+2 <= 100) ? 2*l+2 : 0;

    const float pOO=__expf(cdt[0]),  pOB=__expf(cdt[1]),  pOI=__expf(cdt[2]);
    const float pBO=__expf(cdt[5]),  pBBs=__expf(cdt[6]), pBIs=__expf(cdt[7]),
                pBBd=__expf(cdt[8]), pBId=__expf(cdt[9]);
    const float pIO=__expf(cdt[10]), pIBs=__expf(cdt[11]), pIIs=__expf(cdt[12]),
                pIBd=__expf(cdt[13]), pIId=__expf(cdt[14]);
    const float dBB=pBBs-pBBd, dIB=pIBs-pIBd, dBI=pBIs-pBId, dII=pIIs-pIId;

    // consumer state (r9-verbatim semantics)
    float xB=0.f, xI=0.f, xO=1.f, accF=0.f, uB=0.f, uI=0.f, pOOxO=pOO;
    int accE = 0;
    float f0B=0,f0I=0,f0O=0, f1B=0,f1I=0,f1O=0, f2B=0,f2I=0,f2O=0;
    float gs = 0.f;   // gold partial (wave 2)

    if (wave == 1) {
        // stage chunks 0,1 (rows for steps t=1..32)
        #pragma unroll
        for (int k = 0; k < 2*CHUNK; ++k) {
            const float* row = fb + (size_t)(1 + k) * T;
            float* dst = &S[(size_t)k * 128];
            gl_lds(row + s1, dst);
            gl_lds(row + s2, dst + 64);
        }
    } else if (wave == 0) {
        float pO0 = fb[0] + start_t[0];
        xB = actm * __expf(fb[aB] + start_t[aB] - pO0);
        xI = actm * __expf(fb[aI] + start_t[aI] - pO0);
        accF = pO0;
        uB = __builtin_fmaf(xB, dBB, __builtin_fmaf(xI, dIB, pOB));
        uI = __builtin_fmaf(xB, dBI, __builtin_fmaf(xI, dII, pOI));
    } else {
        if (l == 0) { int tg0 = tb[0]; gs = fb[tg0] + start_t[tg0]; }
    }
    __syncthreads();   // chunks 0,1 staged

    if (wave == 0) {   // pipeline fill: steps 1,2,3 (3-deep LDS->reg pipeline)
        f0B = S[l];         f0I = S[64 + l];         f0O = S[50];
        f1B = S[128 + l];   f1I = S[128 + 64 + l];   f1O = S[128 + 50];
        f2B = S[256 + l];   f2I = S[256 + 64 + l];   f2O = S[256 + 50];
    }

// r9 algebra, re-ordered: the two 6-stage DPP reductions are hand-zipped
// (xB/xI alternating) with all independent per-step work (LDS reads for
// step t+3, the two g-exps, rescale int ops) placed BETWEEN the dependent
// DPP stages in program order -- covers in-order-issue stalls.
#define STEP_BODY(GUARDED)                                                     \
    {                                                                          \
        const int t  = 1 + p * CHUNK + k;                                      \
        const int w3 = ((t + 2) & 63) << 7;   /* slot of step t+3 */           \
        float ra_ = xB, rc_ = xI;                                              \
        ra_ = dpp_xadd<0xB1>(ra_);   rc_ = dpp_xadd<0xB1>(rc_);                \
        float nB_ = S[w3 + l];                                                 \
        ra_ = dpp_xadd<0x4E>(ra_);   rc_ = dpp_xadd<0x4E>(rc_);                \
        float nI_ = S[w3 + 64 + l];                                            \
        ra_ = dpp_xadd<0x141>(ra_);  rc_ = dpp_xadd<0x141>(rc_);               \
        float nO_ = S[w3 + 50];                                                \
        ra_ = dpp_xadd<0x140>(ra_);  rc_ = dpp_xadd<0x140>(rc_);               \
        float gB = actm * __expf(f0B - f0O);                                   \
        ra_ = dpp_xadd<0x142>(ra_);  rc_ = dpp_xadd<0x142>(rc_);               \
        float gI = actm * __expf(f0I - f0O);                                   \
        ra_ = dpp_xadd<0x143>(ra_);  rc_ = dpp_xadd<0x143>(rc_);               \
        int   ke  = ((__float_as_int(xO) >> 23) & 0xFF) - 127;                 \
        float rsc = __int_as_float((127 - ke) << 23);   /* 2^-ke, exact */     \
        float XB = __int_as_float(__builtin_amdgcn_readlane(__float_as_int(ra_), 63)); \
        float XI = __int_as_float(__builtin_amdgcn_readlane(__float_as_int(rc_), 63)); \
        if (!(GUARDED) || t <= nsteps) {                                       \
            float NO = __builtin_fmaf(XI,pIO, __builtin_fmaf(XB,pBO, pOOxO));  \
            float NB = gB * __builtin_fmaf(XI,pIBd, __builtin_fmaf(XB,pBBd, uB)); \
            float NI = gI * __builtin_fmaf(XI,pIId, __builtin_fmaf(XB,pBId, uI)); \
            xB = NB * rsc; xI = NI * rsc; xO = NO * rsc;                       \
            accE += ke;                                                        \
            pOOxO = pOO * xO;                                                  \
            uB = __builtin_fmaf(xB, dBB, __builtin_fmaf(xI, dIB, pOB * xO));   \
            uI = __builtin_fmaf(xB, dBI, __builtin_fmaf(xI, dII, pOI * xO));   \
            accF += f0O;                                                       \
        }                                                                      \
        f0B=f1B; f0I=f1I; f0O=f1O; f1B=f2B; f1I=f2I; f1O=f2O;                  \
        f2B=nB_; f2I=nI_; f2O=nO_;                                             \
    }

    for (int p = 0; p < nper; ++p) {
        if (wave == 0) {
            if (p < nfull) {
                #pragma unroll
                for (int k = 0; k < CHUNK; ++k) STEP_BODY(false)
            } else {
                #pragma unroll
                for (int k = 0; k < CHUNK; ++k) STEP_BODY(true)
            }
        } else if (wave == 1) {
            const int ci = p + 2;                  // stage chunk p+2
            #pragma unroll
            for (int k = 0; k < CHUNK; ++k) {
                int t = 1 + ci * CHUNK + k;
                t = (t < SEQ) ? t : (SEQ - 1);     // clamp; rows beyond len unused
                const float* row = fb + (size_t)t * T;
                float* dst = &S[(size_t)((ci * CHUNK + k) & 63) * 128];
                gl_lds(row + s1, dst);
                gl_lds(row + s2, dst + 64);
            }
        } else {
            // gold wave: chunk p-1 (rows live until period p+1)
            if (p >= 1 && l < CHUNK) {
                int t = 1 + (p - 1) * CHUNK + l;
                if (t <= nsteps) {
                    int tg = tb[t], tp = tb[t - 1];
                    int c1 = (tp == 0) ? 0 : ((tp & 1) ? 1 : 2);
                    int c2 = (tg == 0) ? 0 : ((tg & 1) ? 1 : 2);
                    int si = (tp - 1) >> 1, sj = (tg - 1) >> 1;
                    int t1 = (tp != 0 && si != sj) ? ((c2 == 0) ? 0 : c2 + 2) : c2;
                    gs += cdt[c1 * 5 + t1];
                    int idx = (tg == 0) ? 50 : ((tg & 1) ? ((tg - 1) >> 1) : (64 + ((tg - 2) >> 1)));
                    gs += S[(((t - 1) & 63) << 7) + idx];
                }
            }
        }
        __syncthreads();
    }
#undef STEP_BODY

    if (wave == 0) {
        // forward = accF + ln2*accE + ln( sum_j x_j * exp(stop_j) )
        float W = actm * (xB * __expf(stop_t[aB]) + xI * __expf(stop_t[aI]));
        float tot = wsum64(W) + xO * __expf(stop_t[0]);
        float fwd = accF + 0.69314718055994530942f * (float)accE + __logf(tot);
        if (l == 0) res[0] = fwd;
    } else if (wave == 2) {
        // final chunk (nper-1): its rows are still intact after the loop
        if (l < CHUNK) {
            int t = 1 + (nper - 1) * CHUNK + l;
            if (t >= 1 && t <= nsteps) {
                int tg = tb[t], tp = tb[t - 1];
                int c1 = (tp == 0) ? 0 : ((tp & 1) ? 1 : 2);
                int c2 = (tg == 0) ? 0 : ((tg & 1) ? 1 : 2);
                int si = (tp - 1) >> 1, sj = (tg - 1) >> 1;
                int t1 = (tp != 0 && si != sj) ? ((c2 == 0) ? 0 : c2 + 2) : c2;
                gs += cdt[c1 * 5 + t1];
                int idx = (tg == 0) ? 50 : ((tg & 1) ? ((tg - 1) >> 1) : (64 + ((tg - 2) >> 1)));
                gs += S[(((t - 1) & 63) << 7) + idx];
            }
        }
        float gold = wsum64(gs);
        if (l == 0) res[1] = gold + stop_t[tb[len - 1]];
    }
    __syncthreads();
    if (tid == 0) out[b] = res[0] - res[1];
}

extern "C" void kernel_launch(void* const* d_in, const int* in_sizes, int n_in,
                              void* d_out, int out_size, void* d_ws, size_t ws_size,
                              hipStream_t stream) {
    const float* feats   = (const float*)d_in[0];
    const float* cdt     = (const float*)d_in[1];
    const float* start_t = (const float*)d_in[2];
    const float* stop_t  = (const float*)d_in[3];
    const int*   mask    = (const int*)d_in[4];
    const int*   tags    = (const int*)d_in[5];
    float* out = (float*)d_out;

    crf_nll_kernel<<<256, 192, 0, stream>>>(feats, cdt, start_t, stop_t, mask, tags, out);
}